// Round 3
// baseline (131.280 us; speedup 1.0000x reference)
//
#include <hip/hip_runtime.h>

#define NROWS  32768
#define DDIM   256
#define KCODES 1024

typedef _Float16 half8 __attribute__((ext_vector_type(8)));
typedef float floatx4 __attribute__((ext_vector_type(4)));

// ws layout: [0,4096) f32 cnorm[1024];
//            [4096, 4096+524288) fp16 E' fragment-ready:
//               addr16B = kl*1024 + code   (kl = kc*4+lq, kc 0..7, lq 0..3)
//               chunk holds cb[code][kl*8 .. kl*8+8) as fp16

// ---------------------------------------------------------------------------
// kernel A: codebook row norms, bit-replicating numpy pairwise summation
// (identical to the version that passed R1/R2)
// ---------------------------------------------------------------------------
__global__ void cnorm_np_kernel(const float* __restrict__ cb,
                                float* __restrict__ cnorm) {
    int k = blockIdx.x * blockDim.x + threadIdx.x;
    if (k >= KCODES) return;
    const float* p = cb + (size_t)k * DDIM;
    float halves[2];
    for (int h = 0; h < 2; ++h) {
        const float* a = p + h * 128;
        float r[8];
#pragma unroll
        for (int j = 0; j < 8; ++j) r[j] = __fmul_rn(a[j], a[j]);
        for (int i = 8; i < 128; i += 8) {
#pragma unroll
            for (int j = 0; j < 8; ++j)
                r[j] = __fadd_rn(r[j], __fmul_rn(a[i + j], a[i + j]));
        }
        halves[h] = __fadd_rn(__fadd_rn(__fadd_rn(r[0], r[1]), __fadd_rn(r[2], r[3])),
                              __fadd_rn(__fadd_rn(r[4], r[5]), __fadd_rn(r[6], r[7])));
    }
    cnorm[k] = __fadd_rn(halves[0], halves[1]);
}

// ---------------------------------------------------------------------------
// kernel B: codebook f32 -> fp16, MFMA-A-fragment-ready layout in ws
// ---------------------------------------------------------------------------
__global__ void cvt_cb_kernel(const float* __restrict__ cb,
                              _Float16* __restrict__ ep) {
    int idx  = blockIdx.x * 512 + threadIdx.x;   // 64 blocks x 512 = 32768
    int code = idx & 1023, kl = idx >> 10;       // kl 0..31
    const float4* s = reinterpret_cast<const float4*>(cb + (size_t)code * DDIM + kl * 8);
    float4 a = s[0], b = s[1];
    half8 h;
    h[0] = (_Float16)a.x; h[1] = (_Float16)a.y; h[2] = (_Float16)a.z; h[3] = (_Float16)a.w;
    h[4] = (_Float16)b.x; h[5] = (_Float16)b.y; h[6] = (_Float16)b.z; h[7] = (_Float16)b.w;
    *reinterpret_cast<half8*>(ep + ((size_t)kl * 1024 + code) * 8) = h;
}

// numpy-pairwise ||x||^2 from a global row pointer (passed R2)
__device__ __forceinline__ float xnorm_np_g(const float* __restrict__ p) {
    float halves[2];
    for (int h = 0; h < 2; ++h) {
        const float* a = p + h * 128;
        float r[8];
#pragma unroll
        for (int j = 0; j < 8; ++j) r[j] = __fmul_rn(a[j], a[j]);
        for (int i = 8; i < 128; i += 8) {
#pragma unroll
            for (int j = 0; j < 8; ++j)
                r[j] = __fadd_rn(r[j], __fmul_rn(a[i + j], a[i + j]));
        }
        halves[h] = __fadd_rn(__fadd_rn(__fadd_rn(r[0], r[1]), __fadd_rn(r[2], r[3])),
                              __fadd_rn(__fadd_rn(r[4], r[5]), __fadd_rn(r[6], r[7])));
    }
    return __fadd_rn(halves[0], halves[1]);
}

// ---------------------------------------------------------------------------
// main kernel: 32 rows/block, 4 waves; E streamed global->reg (no barriers in
// the GEMM loop); per-lane top-2; margin fast path + exact refine; gather.
// ---------------------------------------------------------------------------
__global__ __launch_bounds__(256, 3) void som_mfma_kernel(
    const float* __restrict__ x, const float* __restrict__ cb,
    const float* __restrict__ cnorm, const _Float16* __restrict__ ep,
    float* __restrict__ out)
{
    // [0,16K): X fragment-ready (later reused for bmu); [16K,24K) candV; [24K,32K) candI
    __shared__ __align__(16) char smem[32768];
    _Float16* X   = reinterpret_cast<_Float16*>(smem);
    float* candV  = reinterpret_cast<float*>(smem + 16384);
    int*   candI  = reinterpret_cast<int*>(smem + 24576);
    int*   bmu    = reinterpret_cast<int*>(smem);

    const int tid  = threadIdx.x;
    const int lane = tid & 63, w = tid >> 6;      // wave 0..3
    const int l15  = lane & 15, lq = lane >> 4;
    const int row0 = blockIdx.x * 32;

    // ---- stage X (32 rows) -> fp16 fragment-ready LDS, coalesced read ----
    {
        int row = tid >> 3, dslot = tid & 7;      // dslot == kc
        const float4* src = reinterpret_cast<const float4*>(
            x + (size_t)(row0 + row) * DDIM + dslot * 32);
        float4 f[8];
#pragma unroll
        for (int j = 0; j < 8; ++j) f[j] = src[j];
#pragma unroll
        for (int q = 0; q < 4; ++q) {             // q == lq quarter
            float4 A = f[q * 2], B = f[q * 2 + 1];
            half8 h;
            h[0] = (_Float16)A.x; h[1] = (_Float16)A.y; h[2] = (_Float16)A.z; h[3] = (_Float16)A.w;
            h[4] = (_Float16)B.x; h[5] = (_Float16)B.y; h[6] = (_Float16)B.z; h[7] = (_Float16)B.w;
            int a16 = (dslot * 2 + (row >> 4)) * 64 + q * 16 + (row & 15);
            *reinterpret_cast<half8*>(X + a16 * 8) = h;
        }
    }
    __syncthreads();

    const half8* Xv  = reinterpret_cast<const half8*>(X);
    const half8* epv = reinterpret_cast<const half8*>(ep);

    float t1[2], t2[2]; int i1[2], i2[2];
#pragma unroll
    for (int r = 0; r < 2; ++r) { t1[r] = -3.0e38f; t2[r] = -3.0e38f; i1[r] = 0; i2[r] = 0; }

    for (int ct = 0; ct < 2; ++ct) {
        const int cbase = ct * 512 + w * 128;

        floatx4 acc[8][2];
#pragma unroll
        for (int cf = 0; cf < 8; ++cf) {
            acc[cf][0] = (floatx4){0.f, 0.f, 0.f, 0.f};
            acc[cf][1] = (floatx4){0.f, 0.f, 0.f, 0.f};
        }

        half8 eF[2][8];
#pragma unroll
        for (int cf = 0; cf < 8; ++cf)
            eF[0][cf] = epv[(size_t)lq * 1024 + cbase + cf * 16 + l15];

#pragma unroll
        for (int kc = 0; kc < 8; ++kc) {
            const int cur = kc & 1, nxt = cur ^ 1;
            if (kc < 7) {
#pragma unroll
                for (int cf = 0; cf < 8; ++cf)
                    eF[nxt][cf] = epv[(size_t)((kc + 1) * 4 + lq) * 1024 + cbase + cf * 16 + l15];
            }
            half8 xf0 = Xv[(kc * 2 + 0) * 64 + lane];
            half8 xf1 = Xv[(kc * 2 + 1) * 64 + lane];
#pragma unroll
            for (int cf = 0; cf < 8; ++cf) {
                acc[cf][0] = __builtin_amdgcn_mfma_f32_16x16x32_f16(eF[cur][cf], xf0, acc[cf][0], 0, 0, 0);
                acc[cf][1] = __builtin_amdgcn_mfma_f32_16x16x32_f16(eF[cur][cf], xf1, acc[cf][1], 0, 0, 0);
            }
        }

        // ---- epilogue ct: q = dot - cnorm/2, per-lane top-2 ----
#pragma unroll
        for (int cf = 0; cf < 8; ++cf) {
            float4 cn = *reinterpret_cast<const float4*>(cnorm + cbase + cf * 16 + lq * 4);
            float cnl[4] = {cn.x, cn.y, cn.z, cn.w};
#pragma unroll
            for (int reg = 0; reg < 4; ++reg) {
                int code = cbase + cf * 16 + lq * 4 + reg;
#pragma unroll
                for (int rf = 0; rf < 2; ++rf) {
                    float q = acc[cf][rf][reg] - 0.5f * cnl[reg];
                    bool b1 = q > t1[rf], b2 = q > t2[rf];
                    t2[rf] = b1 ? t1[rf] : (b2 ? q : t2[rf]);
                    i2[rf] = b1 ? i1[rf] : (b2 ? code : i2[rf]);
                    t1[rf] = b1 ? q    : t1[rf];
                    i1[rf] = b1 ? code : i1[rf];
                }
            }
        }
    }

    // ---- dump candidates: [32 rows][32 slots] ----
#pragma unroll
    for (int rf = 0; rf < 2; ++rf) {
        int r = rf * 16 + l15;
        int base = r * 32 + (w * 4 + lq) * 2;
        candV[base]     = t1[rf]; candI[base]     = i1[rf];
        candV[base + 1] = t2[rf]; candI[base + 1] = i2[rf];
    }
    __syncthreads();

    // ---- per-row decision: margin fast path or exact refine (2 rows/wave/iter) ----
    const float THR = 1.0e-2f;
    for (int p = 0; p < 4; ++p) {
        int r = p * 8 + w * 2 + (lane >> 5);
        int j = lane & 31;
        float v  = candV[r * 32 + j];
        int   id = candI[r * 32 + j];

        float V1 = v, V2 = -3.0e38f; int I1 = id, I2 = 0;
#pragma unroll
        for (int m = 1; m < 32; m <<= 1) {
            float pv1 = __shfl_xor(V1, m, 64); int pi1 = __shfl_xor(I1, m, 64);
            float pv2 = __shfl_xor(V2, m, 64); int pi2 = __shfl_xor(I2, m, 64);
            bool sw = pv1 > V1;
            float w1 = sw ? pv1 : V1; int wi1 = sw ? pi1 : I1;
            float lo = sw ? V1 : pv1; int loi = sw ? I1 : pi1;
            float s2 = sw ? pv2 : V2; int s2i = sw ? pi2 : I2;
            bool g = lo > s2;
            V1 = w1; I1 = wi1;
            V2 = g ? lo : s2; I2 = g ? loi : s2i;
        }

        int chosen;
        if (2.0f * (V1 - V2) >= THR) {
            chosen = I1;
        } else {
            const float* xr = x + (size_t)(row0 + r) * DDIM;
            const float* cr = cb + (size_t)id * DDIM;
            double m = 0.0;
            for (int d = 0; d < DDIM; ++d)
                m = fma((double)xr[d], (double)cr[d], m);
            float M  = (float)m;
            float xn = xnorm_np_g(xr);
            float s  = __fsub_rn(__fadd_rn(xn, cnorm[id]), __fmul_rn(2.0f, M));
#pragma unroll
            for (int m2 = 1; m2 < 32; m2 <<= 1) {
                float ps = __shfl_xor(s, m2, 64); int pid = __shfl_xor(id, m2, 64);
                bool take = (ps < s) || (ps == s && pid < id);
                s  = take ? ps  : s;
                id = take ? pid : id;
            }
            chosen = id;
        }
        if (j == 0) bmu[r] = chosen;
    }
    __syncthreads();

    // ---- gather: out[row] = codebook[bmu[row]] ----
    float4* out4 = reinterpret_cast<float4*>(out);
    const float4* cb4 = reinterpret_cast<const float4*>(cb);
#pragma unroll
    for (int p = 0; p < 8; ++p) {
        int idx = p * 256 + tid;
        int r = idx >> 6, sl = idx & 63;
        int code = bmu[r];
        out4[(size_t)(row0 + r) * 64 + sl] = cb4[(size_t)code * 64 + sl];
    }
}

extern "C" void kernel_launch(void* const* d_in, const int* in_sizes, int n_in,
                              void* d_out, int out_size, void* d_ws, size_t ws_size,
                              hipStream_t stream) {
    const float* x  = (const float*)d_in[0];
    const float* cb = (const float*)d_in[1];
    float* out = (float*)d_out;

    float*    cnorm = (float*)d_ws;
    _Float16* ep    = (_Float16*)((char*)d_ws + 4096);

    cnorm_np_kernel<<<dim3(4), dim3(256), 0, stream>>>(cb, cnorm);
    cvt_cb_kernel<<<dim3(64), dim3(512), 0, stream>>>(cb, ep);
    som_mfma_kernel<<<dim3(1024), dim3(256), 0, stream>>>(x, cb, cnorm, ep, out);
}

// Round 4
// 74.263 us; speedup vs baseline: 1.7678x; 1.7678x over previous
//
#include <hip/hip_runtime.h>

#define NROWS  32768
#define DDIM   256
#define KCODES 1024

typedef _Float16 half8 __attribute__((ext_vector_type(8)));
typedef float floatx4 __attribute__((ext_vector_type(4)));
typedef __attribute__((address_space(3))) void lds_void;
typedef __attribute__((address_space(1))) const void glb_cvoid;

// ws layout: [0,4096) f32 cnorm[1024];
//            [4096, 4096+524288) fp16 E' chunk-major fragment-ready:
//   chunk t = ct*8+dc (ct: 256-code tile, dc: 32-depth slice), 16 KB each.
//   within chunk: 16B slot s = lq*256 + coderel  holds fp16 of
//   cb[ct*256+coderel][dc*32 + lq*8 .. +8)

// ---------------------------------------------------------------------------
// kernel A: codebook row norms, bit-replicating numpy pairwise summation
// (identical to the version that passed R1-R3)
// ---------------------------------------------------------------------------
__global__ void cnorm_np_kernel(const float* __restrict__ cb,
                                float* __restrict__ cnorm) {
    int k = blockIdx.x * blockDim.x + threadIdx.x;
    if (k >= KCODES) return;
    const float* p = cb + (size_t)k * DDIM;
    float halves[2];
    for (int h = 0; h < 2; ++h) {
        const float* a = p + h * 128;
        float r[8];
#pragma unroll
        for (int j = 0; j < 8; ++j) r[j] = __fmul_rn(a[j], a[j]);
        for (int i = 8; i < 128; i += 8) {
#pragma unroll
            for (int j = 0; j < 8; ++j)
                r[j] = __fadd_rn(r[j], __fmul_rn(a[i + j], a[i + j]));
        }
        halves[h] = __fadd_rn(__fadd_rn(__fadd_rn(r[0], r[1]), __fadd_rn(r[2], r[3])),
                              __fadd_rn(__fadd_rn(r[4], r[5]), __fadd_rn(r[6], r[7])));
    }
    cnorm[k] = __fadd_rn(halves[0], halves[1]);
}

// ---------------------------------------------------------------------------
// kernel B: codebook f32 -> fp16, chunk-major lane-linear layout (see above)
// ---------------------------------------------------------------------------
__global__ void cvt_cb_kernel(const float* __restrict__ cb,
                              _Float16* __restrict__ ep) {
    int idx  = blockIdx.x * 512 + threadIdx.x;   // 64 x 512 = 32768
    int code = idx >> 5, kl = idx & 31;          // kl = dc*4+lq
    int dc = kl >> 2, lq = kl & 3;
    int ct = code >> 8, cr = code & 255;
    const float4* s = reinterpret_cast<const float4*>(cb + (size_t)code * DDIM + kl * 8);
    float4 a = s[0], b = s[1];
    half8 h;
    h[0] = (_Float16)a.x; h[1] = (_Float16)a.y; h[2] = (_Float16)a.z; h[3] = (_Float16)a.w;
    h[4] = (_Float16)b.x; h[5] = (_Float16)b.y; h[6] = (_Float16)b.z; h[7] = (_Float16)b.w;
    size_t slot = (size_t)(ct * 8 + dc) * 1024 + lq * 256 + cr;
    *reinterpret_cast<half8*>(ep + slot * 8) = h;
}

// numpy-pairwise ||x||^2 from a global row pointer (passed R2/R3)
__device__ __forceinline__ float xnorm_np_g(const float* __restrict__ p) {
    float halves[2];
    for (int h = 0; h < 2; ++h) {
        const float* a = p + h * 128;
        float r[8];
#pragma unroll
        for (int j = 0; j < 8; ++j) r[j] = __fmul_rn(a[j], a[j]);
        for (int i = 8; i < 128; i += 8) {
#pragma unroll
            for (int j = 0; j < 8; ++j)
                r[j] = __fadd_rn(r[j], __fmul_rn(a[i + j], a[i + j]));
        }
        halves[h] = __fadd_rn(__fadd_rn(__fadd_rn(r[0], r[1]), __fadd_rn(r[2], r[3])),
                              __fadd_rn(__fadd_rn(r[4], r[5]), __fadd_rn(r[6], r[7])));
    }
    return __fadd_rn(halves[0], halves[1]);
}

// ---------------------------------------------------------------------------
// main kernel: 64 rows/block x 1024 codes; E double-buffered in LDS via
// global_load_lds (2-phase schedule, 1 barrier/step); per-lane top-2;
// margin fast path + exact refine; gather. 64 KB LDS -> 2 blocks/CU.
// ---------------------------------------------------------------------------
__global__ __launch_bounds__(512, 4) void som_mfma_kernel(
    const float* __restrict__ x, const float* __restrict__ cb,
    const float* __restrict__ cnorm, const _Float16* __restrict__ ep,
    float* __restrict__ out)
{
    __shared__ __align__(16) char smem[65536];
    _Float16* X  = reinterpret_cast<_Float16*>(smem);        // 32 KB
    char* EB0    = smem + 32768;                              // 16 KB
    char* EB1    = smem + 49152;                              // 16 KB
    float* candV = reinterpret_cast<float*>(smem + 32768);    // reuse EB0
    int*   candI = reinterpret_cast<int*>(smem + 40960);
    int*   bmu   = reinterpret_cast<int*>(smem);              // reuse X

    const int tid  = threadIdx.x;
    const int lane = tid & 63, w = tid >> 6;       // wave 0..7
    const int l15  = lane & 15, lq = lane >> 4;
    const int cq   = w & 3, rh = w >> 2;           // code strip (256), row half (32)
    const int row0 = blockIdx.x * 64;

    const char* epc = (const char*)ep;

    // ---- stage X (64 rows) -> fp16 fragment-ready LDS ----
    {
        int row = tid >> 3, dslot = tid & 7;
        const float4* src = reinterpret_cast<const float4*>(
            x + (size_t)(row0 + row) * DDIM + dslot * 32);
        float4 f[8];
#pragma unroll
        for (int j = 0; j < 8; ++j) f[j] = src[j];
#pragma unroll
        for (int q = 0; q < 4; ++q) {
            float4 A = f[q * 2], B = f[q * 2 + 1];
            half8 h;
            h[0] = (_Float16)A.x; h[1] = (_Float16)A.y; h[2] = (_Float16)A.z; h[3] = (_Float16)A.w;
            h[4] = (_Float16)B.x; h[5] = (_Float16)B.y; h[6] = (_Float16)B.z; h[7] = (_Float16)B.w;
            int a16 = (dslot * 4 + (row >> 4)) * 64 + q * 16 + (row & 15);
            *reinterpret_cast<half8*>(X + a16 * 8) = h;
        }
    }

    // ---- prologue: stage E chunk 0 ----
    {
        const char* g = epc + ((size_t)w << 11) + (lane << 4);
        char* l = EB0 + (w << 11);
        __builtin_amdgcn_global_load_lds((glb_cvoid*)g, (lds_void*)l, 16, 0, 0);
        __builtin_amdgcn_global_load_lds((glb_cvoid*)(g + 1024), (lds_void*)(l + 1024), 16, 0, 0);
    }
    __syncthreads();

    const half8* Xv = reinterpret_cast<const half8*>(X);

    float t1[2], t2[2]; int i1[2], i2[2];
#pragma unroll
    for (int r = 0; r < 2; ++r) { t1[r] = -3.0e38f; t2[r] = -3.0e38f; i1[r] = 0; i2[r] = 0; }

    for (int ct = 0; ct < 4; ++ct) {
        floatx4 acc[4][2];
#pragma unroll
        for (int cf = 0; cf < 4; ++cf) {
            acc[cf][0] = (floatx4){0.f, 0.f, 0.f, 0.f};
            acc[cf][1] = (floatx4){0.f, 0.f, 0.f, 0.f};
        }

#pragma unroll
        for (int dc = 0; dc < 8; ++dc) {
            const int t = ct * 8 + dc;
            char* cur = (t & 1) ? EB1 : EB0;
            char* nxt = (t & 1) ? EB0 : EB1;

            if (t < 31) {   // stage next chunk (lands before next step's barrier)
                const char* g = epc + ((size_t)(t + 1) << 14) + ((size_t)w << 11) + (lane << 4);
                char* l = nxt + (w << 11);
                __builtin_amdgcn_global_load_lds((glb_cvoid*)g, (lds_void*)l, 16, 0, 0);
                __builtin_amdgcn_global_load_lds((glb_cvoid*)(g + 1024), (lds_void*)(l + 1024), 16, 0, 0);
            }

            const half8* Ev = reinterpret_cast<const half8*>(cur);
            half8 eF[4], xf[2];
#pragma unroll
            for (int cf = 0; cf < 4; ++cf)
                eF[cf] = Ev[lq * 256 + cq * 64 + cf * 16 + l15];
#pragma unroll
            for (int rf = 0; rf < 2; ++rf)
                xf[rf] = Xv[(dc * 4 + rh * 2 + rf) * 64 + lane];

#pragma unroll
            for (int cf = 0; cf < 4; ++cf) {
                acc[cf][0] = __builtin_amdgcn_mfma_f32_16x16x32_f16(eF[cf], xf[0], acc[cf][0], 0, 0, 0);
                acc[cf][1] = __builtin_amdgcn_mfma_f32_16x16x32_f16(eF[cf], xf[1], acc[cf][1], 0, 0, 0);
            }

            __syncthreads();   // drains vmcnt (stage) + lgkm; 2 blocks/CU overlap
        }

        // ---- epilogue ct: q = dot - cnorm/2, per-lane top-2 (registers only) ----
#pragma unroll
        for (int cf = 0; cf < 4; ++cf) {
            const int cb0 = ct * 256 + cq * 64 + cf * 16 + lq * 4;
            float4 cn = *reinterpret_cast<const float4*>(cnorm + cb0);
            float cnl[4] = {cn.x, cn.y, cn.z, cn.w};
#pragma unroll
            for (int reg = 0; reg < 4; ++reg) {
                int code = cb0 + reg;
#pragma unroll
                for (int rf = 0; rf < 2; ++rf) {
                    float q = acc[cf][rf][reg] - 0.5f * cnl[reg];
                    bool b1 = q > t1[rf], b2 = q > t2[rf];
                    t2[rf] = b1 ? t1[rf] : (b2 ? q : t2[rf]);
                    i2[rf] = b1 ? i1[rf] : (b2 ? code : i2[rf]);
                    t1[rf] = b1 ? q    : t1[rf];
                    i1[rf] = b1 ? code : i1[rf];
                }
            }
        }
    }

    // ---- dump candidates: [64 rows][32 slots] (reuses E region; all EB reads
    //      finished at the t=31 barrier) ----
#pragma unroll
    for (int rf = 0; rf < 2; ++rf) {
        int r = rh * 32 + rf * 16 + l15;
        int base = r * 32 + (cq * 4 + lq) * 2;
        candV[base]     = t1[rf]; candI[base]     = i1[rf];
        candV[base + 1] = t2[rf]; candI[base + 1] = i2[rf];
    }
    __syncthreads();

    // ---- per-row decision: margin fast path or exact refine ----
    const float THR = 1.0e-2f;
    for (int p = 0; p < 4; ++p) {
        int r = p * 16 + w * 2 + (lane >> 5);
        int j = lane & 31;
        float v  = candV[r * 32 + j];
        int   id = candI[r * 32 + j];

        float V1 = v, V2 = -3.0e38f; int I1 = id, I2 = 0;
#pragma unroll
        for (int m = 1; m < 32; m <<= 1) {
            float pv1 = __shfl_xor(V1, m, 64); int pi1 = __shfl_xor(I1, m, 64);
            float pv2 = __shfl_xor(V2, m, 64); int pi2 = __shfl_xor(I2, m, 64);
            bool sw = pv1 > V1;
            float w1 = sw ? pv1 : V1; int wi1 = sw ? pi1 : I1;
            float lo = sw ? V1 : pv1; int loi = sw ? I1 : pi1;
            float s2 = sw ? pv2 : V2; int s2i = sw ? pi2 : I2;
            bool g = lo > s2;
            V1 = w1; I1 = wi1;
            V2 = g ? lo : s2; I2 = g ? loi : s2i;
        }

        int chosen;
        if (2.0f * (V1 - V2) >= THR) {
            chosen = I1;
        } else {
            const float* xr = x + (size_t)(row0 + r) * DDIM;
            const float* cr = cb + (size_t)id * DDIM;
            double m = 0.0;
            for (int d = 0; d < DDIM; ++d)
                m = fma((double)xr[d], (double)cr[d], m);
            float M  = (float)m;
            float xn = xnorm_np_g(xr);
            float s  = __fsub_rn(__fadd_rn(xn, cnorm[id]), __fmul_rn(2.0f, M));
#pragma unroll
            for (int m2 = 1; m2 < 32; m2 <<= 1) {
                float ps = __shfl_xor(s, m2, 64); int pid = __shfl_xor(id, m2, 64);
                bool take = (ps < s) || (ps == s && pid < id);
                s  = take ? ps  : s;
                id = take ? pid : id;
            }
            chosen = id;
        }
        if (j == 0) bmu[r] = chosen;
    }
    __syncthreads();

    // ---- gather: out[row] = codebook[bmu[row]] ----
    float4* out4 = reinterpret_cast<float4*>(out);
    const float4* cb4 = reinterpret_cast<const float4*>(cb);
#pragma unroll
    for (int p = 0; p < 8; ++p) {
        int idx = p * 512 + tid;
        int r = idx >> 6, sl = idx & 63;
        int code = bmu[r];
        out4[(size_t)(row0 + r) * 64 + sl] = cb4[(size_t)code * 64 + sl];
    }
}

extern "C" void kernel_launch(void* const* d_in, const int* in_sizes, int n_in,
                              void* d_out, int out_size, void* d_ws, size_t ws_size,
                              hipStream_t stream) {
    const float* x  = (const float*)d_in[0];
    const float* cb = (const float*)d_in[1];
    float* out = (float*)d_out;

    float*    cnorm = (float*)d_ws;
    _Float16* ep    = (_Float16*)((char*)d_ws + 4096);

    cnorm_np_kernel<<<dim3(4), dim3(256), 0, stream>>>(cb, cnorm);
    cvt_cb_kernel<<<dim3(64), dim3(512), 0, stream>>>(cb, ep);
    som_mfma_kernel<<<dim3(512), dim3(512), 0, stream>>>(x, cb, cnorm, ep, out);
}

// Round 5
// 60.274 us; speedup vs baseline: 2.1780x; 1.2321x over previous
//
#include <hip/hip_runtime.h>

#define NROWS  32768
#define DDIM   256
#define KCODES 1024

typedef _Float16 half8 __attribute__((ext_vector_type(8)));
typedef float floatx4 __attribute__((ext_vector_type(4)));

// ws layout: [0,4096) f32 cnorm[1024];
//            [4096, 4096+524288) fp16 E' chunk-major fragment-ready:
//   16B slot = (ct*8 + kc)*1024 + lq*256 + cr   holds fp16 of
//   cb[ct*256+cr][kc*32 + lq*8 .. +8)

// ---------------------------------------------------------------------------
// prep kernel: codebook f32 -> fp16 fragment layout (validated R4) + cnorm
// (np-pairwise-replicated, validated R1-R4) folded into the same launch.
// ---------------------------------------------------------------------------
__global__ void prep_kernel(const float* __restrict__ cb,
                            float* __restrict__ cnorm,
                            _Float16* __restrict__ ep) {
    int idx  = blockIdx.x * 512 + threadIdx.x;   // 64 x 512 = 32768
    int code = idx >> 5, kl = idx & 31;
    int dc = kl >> 2, lq = kl & 3;
    int ct = code >> 8, cr = code & 255;
    const float4* s = reinterpret_cast<const float4*>(cb + (size_t)code * DDIM + kl * 8);
    float4 a = s[0], b = s[1];
    half8 h;
    h[0] = (_Float16)a.x; h[1] = (_Float16)a.y; h[2] = (_Float16)a.z; h[3] = (_Float16)a.w;
    h[4] = (_Float16)b.x; h[5] = (_Float16)b.y; h[6] = (_Float16)b.z; h[7] = (_Float16)b.w;
    size_t slot = (size_t)(ct * 8 + dc) * 1024 + lq * 256 + cr;
    *reinterpret_cast<half8*>(ep + slot * 8) = h;

    if (threadIdx.x < 16) {
        int k = blockIdx.x * 16 + threadIdx.x;
        const float* p = cb + (size_t)k * DDIM;
        float halves[2];
        for (int hh = 0; hh < 2; ++hh) {
            const float* aa = p + hh * 128;
            float r[8];
#pragma unroll
            for (int j = 0; j < 8; ++j) r[j] = __fmul_rn(aa[j], aa[j]);
            for (int i = 8; i < 128; i += 8) {
#pragma unroll
                for (int j = 0; j < 8; ++j)
                    r[j] = __fadd_rn(r[j], __fmul_rn(aa[i + j], aa[i + j]));
            }
            halves[hh] = __fadd_rn(__fadd_rn(__fadd_rn(r[0], r[1]), __fadd_rn(r[2], r[3])),
                                   __fadd_rn(__fadd_rn(r[4], r[5]), __fadd_rn(r[6], r[7])));
        }
        cnorm[k] = __fadd_rn(halves[0], halves[1]);
    }
}

// numpy-pairwise ||x||^2 from a global row pointer (validated R2-R4)
__device__ __forceinline__ float xnorm_np_g(const float* __restrict__ p) {
    float halves[2];
    for (int h = 0; h < 2; ++h) {
        const float* a = p + h * 128;
        float r[8];
#pragma unroll
        for (int j = 0; j < 8; ++j) r[j] = __fmul_rn(a[j], a[j]);
        for (int i = 8; i < 128; i += 8) {
#pragma unroll
            for (int j = 0; j < 8; ++j)
                r[j] = __fadd_rn(r[j], __fmul_rn(a[i + j], a[i + j]));
        }
        halves[h] = __fadd_rn(__fadd_rn(__fadd_rn(r[0], r[1]), __fadd_rn(r[2], r[3])),
                              __fadd_rn(__fadd_rn(r[4], r[5]), __fadd_rn(r[6], r[7])));
    }
    return __fadd_rn(halves[0], halves[1]);
}

// ---------------------------------------------------------------------------
// main kernel: 64 rows/block, 4 waves x 256-code strips. X panel lives in
// registers (128 VGPR/wave); E' streams L2->reg with half-frag prefetch.
// ZERO barriers / LDS traffic in the main loop. Top-2 + margin fast path +
// exact refine + gather (all validated R2-R4).
// ---------------------------------------------------------------------------
__global__ __launch_bounds__(256, 2) void som_mfma_kernel(
    const float* __restrict__ x, const float* __restrict__ cb,
    const float* __restrict__ cnorm, const _Float16* __restrict__ ep,
    float* __restrict__ out)
{
    __shared__ __align__(16) char smem[32768];

    const int tid  = threadIdx.x;
    const int lane = tid & 63, w = tid >> 6;     // wave 0..3 = code strip
    const int l15  = lane & 15, lq = lane >> 4;
    const int row0 = blockIdx.x * 64;

    // ---- stage X (64 rows) coalesced -> fp16 fragment layout in LDS ----
    {
        int row = tid >> 2, qd = tid & 3;
        const float4* src = reinterpret_cast<const float4*>(
            x + (size_t)(row0 + row) * DDIM + qd * 64);
        float4 f[16];
#pragma unroll
        for (int i = 0; i < 16; ++i) f[i] = src[i];
        half8* X16 = reinterpret_cast<half8*>(smem);
#pragma unroll
        for (int j = 0; j < 8; ++j) {
            float4 A = f[2 * j], B = f[2 * j + 1];
            half8 h;
            h[0] = (_Float16)A.x; h[1] = (_Float16)A.y; h[2] = (_Float16)A.z; h[3] = (_Float16)A.w;
            h[4] = (_Float16)B.x; h[5] = (_Float16)B.y; h[6] = (_Float16)B.z; h[7] = (_Float16)B.w;
            X16[(qd * 8 + j) * 64 + row] = h;   // [kq 0..31][row 0..63]
        }
    }
    __syncthreads();

    // ---- X panel -> registers: 4 row-frags x 8 k-chunks (128 VGPR) ----
    half8 xr0[8], xr1[8], xr2[8], xr3[8];
    {
        const half8* X16 = reinterpret_cast<const half8*>(smem);
#pragma unroll
        for (int kc = 0; kc < 8; ++kc) {
            int base = (kc * 4 + lq) * 64 + l15;
            xr0[kc] = X16[base];
            xr1[kc] = X16[base + 16];
            xr2[kc] = X16[base + 32];
            xr3[kc] = X16[base + 48];
        }
    }
    __syncthreads();   // X LDS dead from here

    const half8* epv = reinterpret_cast<const half8*>(ep);
    const int ebase = w * 8192 + lq * 256 + l15;    // 16B-slot units
    const int codebase = w * 256 + lq * 4;

    half8 eF[2][4];
#pragma unroll
    for (int j = 0; j < 4; ++j) eF[0][j] = epv[ebase + j * 1024];   // cf0, kc0-3

    float t1[4], t2[4]; int i1[4], i2[4];
#pragma unroll
    for (int r = 0; r < 4; ++r) { t1[r] = -3.0e38f; t2[r] = -3.0e38f; i1[r] = 0; i2[r] = 0; }

#pragma unroll
    for (int cf = 0; cf < 16; ++cf) {
        floatx4 a0 = {0.f, 0.f, 0.f, 0.f}, a1 = a0, a2 = a0, a3 = a0;

#pragma unroll
        for (int h = 0; h < 2; ++h) {
            const int cfh = cf * 2 + h;
            if (cfh < 31) {   // prefetch next half-frag (4 x dwordx4 from L2)
                const int ncf = (cfh + 1) >> 1, nh = (cfh + 1) & 1;
#pragma unroll
                for (int j = 0; j < 4; ++j)
                    eF[(cfh + 1) & 1][j] = epv[ebase + (nh * 4 + j) * 1024 + ncf * 16];
            }
#pragma unroll
            for (int j = 0; j < 4; ++j) {
                const int kc = h * 4 + j;
                half8 e = eF[cfh & 1][j];
                a0 = __builtin_amdgcn_mfma_f32_16x16x32_f16(e, xr0[kc], a0, 0, 0, 0);
                a1 = __builtin_amdgcn_mfma_f32_16x16x32_f16(e, xr1[kc], a1, 0, 0, 0);
                a2 = __builtin_amdgcn_mfma_f32_16x16x32_f16(e, xr2[kc], a2, 0, 0, 0);
                a3 = __builtin_amdgcn_mfma_f32_16x16x32_f16(e, xr3[kc], a3, 0, 0, 0);
            }
        }

        // ---- epilogue cf: q = dot - cnorm/2, per-lane top-2 per row-frag ----
        float4 cn = *reinterpret_cast<const float4*>(cnorm + w * 256 + cf * 16 + lq * 4);
        float cnl[4] = {cn.x, cn.y, cn.z, cn.w};
#pragma unroll
        for (int reg = 0; reg < 4; ++reg) {
            const int code = codebase + cf * 16 + reg;
#define TOP2(AV, RF) { float q = (AV) - 0.5f * cnl[reg];                        \
                       bool b1 = q > t1[RF], b2 = q > t2[RF];                   \
                       t2[RF] = b1 ? t1[RF] : (b2 ? q : t2[RF]);                \
                       i2[RF] = b1 ? i1[RF] : (b2 ? code : i2[RF]);             \
                       t1[RF] = b1 ? q : t1[RF];                                \
                       i1[RF] = b1 ? code : i1[RF]; }
            TOP2(a0[reg], 0)
            TOP2(a1[reg], 1)
            TOP2(a2[reg], 2)
            TOP2(a3[reg], 3)
#undef TOP2
        }
    }

    // ---- dump candidates: [64 rows][32 slots] (reuses X LDS) ----
    float* candV = reinterpret_cast<float*>(smem);           // 8 KB
    int*   candI = reinterpret_cast<int*>(smem + 8192);      // 8 KB
    int*   bmu   = reinterpret_cast<int*>(smem + 16384);
#pragma unroll
    for (int rf = 0; rf < 4; ++rf) {
        int r = rf * 16 + l15;
        int base = r * 32 + (w * 4 + lq) * 2;
        candV[base]     = t1[rf]; candI[base]     = i1[rf];
        candV[base + 1] = t2[rf]; candI[base + 1] = i2[rf];
    }
    __syncthreads();

    // ---- per-row decision: margin fast path or exact refine (validated) ----
    const float THR = 1.0e-2f;
    for (int p = 0; p < 8; ++p) {
        int r = p * 8 + w * 2 + (lane >> 5);
        int j = lane & 31;
        float v  = candV[r * 32 + j];
        int   id = candI[r * 32 + j];

        float V1 = v, V2 = -3.0e38f; int I1 = id, I2 = 0;
#pragma unroll
        for (int m = 1; m < 32; m <<= 1) {
            float pv1 = __shfl_xor(V1, m, 64); int pi1 = __shfl_xor(I1, m, 64);
            float pv2 = __shfl_xor(V2, m, 64); int pi2 = __shfl_xor(I2, m, 64);
            bool sw = pv1 > V1;
            float w1 = sw ? pv1 : V1; int wi1 = sw ? pi1 : I1;
            float lo = sw ? V1 : pv1; int loi = sw ? I1 : pi1;
            float s2 = sw ? pv2 : V2; int s2i = sw ? pi2 : I2;
            bool g = lo > s2;
            V1 = w1; I1 = wi1;
            V2 = g ? lo : s2; I2 = g ? loi : s2i;
        }

        int chosen;
        if (2.0f * (V1 - V2) >= THR) {
            chosen = I1;
        } else {
            const float* xr = x + (size_t)(row0 + r) * DDIM;
            const float* cr = cb + (size_t)id * DDIM;
            double m = 0.0;
            for (int d = 0; d < DDIM; ++d)
                m = fma((double)xr[d], (double)cr[d], m);
            float M  = (float)m;
            float xn = xnorm_np_g(xr);
            float s  = __fsub_rn(__fadd_rn(xn, cnorm[id]), __fmul_rn(2.0f, M));
#pragma unroll
            for (int m2 = 1; m2 < 32; m2 <<= 1) {
                float ps = __shfl_xor(s, m2, 64); int pid = __shfl_xor(id, m2, 64);
                bool take = (ps < s) || (ps == s && pid < id);
                s  = take ? ps  : s;
                id = take ? pid : id;
            }
            chosen = id;
        }
        if (j == 0) bmu[r] = chosen;
    }
    __syncthreads();

    // ---- gather: out[row] = codebook[bmu[row]] ----
    float4* out4 = reinterpret_cast<float4*>(out);
    const float4* cb4 = reinterpret_cast<const float4*>(cb);
#pragma unroll
    for (int p = 0; p < 16; ++p) {
        int idx = p * 256 + tid;
        int r = idx >> 6, sl = idx & 63;
        int code = bmu[r];
        out4[(size_t)(row0 + r) * 64 + sl] = cb4[(size_t)code * 64 + sl];
    }
}

extern "C" void kernel_launch(void* const* d_in, const int* in_sizes, int n_in,
                              void* d_out, int out_size, void* d_ws, size_t ws_size,
                              hipStream_t stream) {
    const float* x  = (const float*)d_in[0];
    const float* cb = (const float*)d_in[1];
    float* out = (float*)d_out;

    float*    cnorm = (float*)d_ws;
    _Float16* ep    = (_Float16*)((char*)d_ws + 4096);

    prep_kernel<<<dim3(64), dim3(512), 0, stream>>>(cb, cnorm, ep);
    som_mfma_kernel<<<dim3(512), dim3(256), 0, stream>>>(x, cb, cnorm, ep, out);
}